// Round 8
// baseline (486.094 us; speedup 1.0000x reference)
//
#include <hip/hip_runtime.h>

// Caps layer B=256, S=512, D=256, NC=16, DC=32, O=512 — 6-dispatch graph.
// Constraint found r3-r7: one block per batch = 8 waves/CU (2/SIMD) is
// latency-starved (VALUBusy<19%, HBM<26%); fused single-kernel made it worse
// (serial MFMA->softmax->y chain kills MLP). Fix: split each batch's s-range
// across 2 blocks (16 waves/CU on the heavy x-streams) and cut the kernel at
// the two reduction boundaries (y needs all-s, b needs all-D) into separate
// dispatches — stream order guarantees cross-block visibility, no atomics.
//   k_part0: partial rowsum                      (512 blk, reads x once)
//   k_oz(i): y=sum(partials) -> outputs,squash -> z (256 blk, W-GEMMs)
//   k_by   : fused b-MFMA -> softmax -> partial y (512 blk, reads x once)
// ws: y-partials f32 [256][2][16][256] = 8 MB; z bf16 [256][16][264] = 2.1 MB.
// LESSON (r4,r6): no runtime-variable indices into register arrays (spills).

#define S_ 512
#define D_ 256
#define O_ 512

typedef __attribute__((ext_vector_type(8))) short short8;
typedef __attribute__((ext_vector_type(4))) float floatx4;

#define YPART_OFF 0                        // f32 [b][q][n][D]  (k_part0: [b][q][D])
#define ZWS_OFF   (256 * 2 * 16 * 256)     // float index; zws = ushort [b][16][264]

__device__ __forceinline__ unsigned short f2b(float f) {
  union { float ff; unsigned int i; } v; v.ff = f;
  unsigned int u = v.i;
  return (unsigned short)((u + 0x7FFFu + ((u >> 16) & 1u)) >> 16);
}

// ---------------- k_part0: partial rowsum over 256-s half ----------------
__global__ __launch_bounds__(512, 4) void k_part0(
    const float* __restrict__ x, float* __restrict__ ws)
{
  __shared__ __align__(16) float strip[8 * 256];
  const int tid = threadIdx.x, wave = tid >> 6, lane = tid & 63;
  const int b = blockIdx.x >> 1, q = blockIdx.x & 1;
  const float* xb = x + (size_t)b * (S_ * D_);

  float a0 = 0.f, a1 = 0.f, a2 = 0.f, a3 = 0.f;
  #pragma unroll 4
  for (int r = 0; r < 32; ++r) {
    const int s = (q << 8) + (wave << 5) + r;
    const float4 xv = *(const float4*)(xb + s * D_ + (lane << 2));
    a0 += xv.x; a1 += xv.y; a2 += xv.z; a3 += xv.w;
  }
  *(float4*)(strip + wave * 256 + (lane << 2)) = make_float4(a0, a1, a2, a3);
  __syncthreads();
  if (tid < 256) {
    float v = 0.f;
    #pragma unroll
    for (int w = 0; w < 8; ++w) v += strip[w * 256 + tid];
    ws[YPART_OFF + b * 512 + q * 256 + tid] = v;   // y0 partial (n-independent)
  }
}

// ---------------- k_oz: y -> outputs -> squash -> z (modes 0/1/2) ----------------
__global__ __launch_bounds__(512, 2) void k_oz(
    const float* __restrict__ W, float* __restrict__ ws,
    float* __restrict__ out, int iter)
{
  __shared__ __align__(16) float ytmp[16 * 260];
  __shared__ __align__(16) float outp[O_];
  const int tid = threadIdx.x, wave = tid >> 6, lane = tid & 63;
  const int b = blockIdx.x;

  // stage y into LDS
  if (iter == 0) {
    if (tid < 256) {
      const float v = (ws[YPART_OFF + b * 512 + tid] +
                       ws[YPART_OFF + b * 512 + 256 + tid]) * 0.0625f;
      #pragma unroll
      for (int n = 0; n < 16; ++n) ytmp[n * 260 + tid] = v;
    }
  } else {
    const int n = tid >> 5, d0 = (tid & 31) << 3;
    const float* p0 = ws + YPART_OFF + ((size_t)(b * 2 + 0) * 16 + n) * 256 + d0;
    const float* p1 = ws + YPART_OFF + ((size_t)(b * 2 + 1) * 16 + n) * 256 + d0;
    const float4 a0 = *(const float4*)p0,       a1 = *(const float4*)(p0 + 4);
    const float4 b0 = *(const float4*)p1,       b1 = *(const float4*)(p1 + 4);
    *(float4*)(ytmp + n * 260 + d0)     = make_float4(a0.x+b0.x, a0.y+b0.y, a0.z+b0.z, a0.w+b0.w);
    *(float4*)(ytmp + n * 260 + d0 + 4) = make_float4(a1.x+b1.x, a1.y+b1.y, a1.z+b1.z, a1.w+b1.w);
  }
  __syncthreads();

  // outputs[n][d] = sum_D y[n][D] W[D][n*32+d]; squash over d (32-lane groups)
  {
    const int o = tid, n = o >> 5;
    float a = 0.f;
    for (int Db = 0; Db < 32; ++Db) {
      const float4 y0 = *(const float4*)(ytmp + n * 260 + (Db << 3));
      const float4 y1 = *(const float4*)(ytmp + n * 260 + (Db << 3) + 4);
      const float* wp = W + (size_t)(Db << 3) * O_ + o;
      a += y0.x * wp[0 * O_]; a += y0.y * wp[1 * O_];
      a += y0.z * wp[2 * O_]; a += y0.w * wp[3 * O_];
      a += y1.x * wp[4 * O_]; a += y1.y * wp[5 * O_];
      a += y1.z * wp[6 * O_]; a += y1.w * wp[7 * O_];
    }
    float ss = a * a;
    #pragma unroll
    for (int off = 1; off < 32; off <<= 1) ss += __shfl_xor(ss, off, 64);
    const float v = a / sqrtf(ss + 1e-7f);
    outp[o] = v;
    if (iter == 2) out[(size_t)b * O_ + o] = v;
  }
  __syncthreads();

  if (iter < 2) {
    // z[n][D] = sum_d W[D][n*32+d] outputs[n][d]; wave owns 32 D-rows
    unsigned short* zws = (unsigned short*)(ws + ZWS_OFF) + (size_t)b * 4224;
    const int obase = lane << 3, n_ln = lane >> 2;
    float ov[8];
    #pragma unroll
    for (int j = 0; j < 8; ++j) ov[j] = outp[obase + j];
    for (int r = 0; r < 32; ++r) {
      const int Dd = (wave << 5) + r;
      const float4 w0 = *(const float4*)(W + (size_t)Dd * O_ + obase);
      const float4 w1 = *(const float4*)(W + (size_t)Dd * O_ + obase + 4);
      float a = w0.x * ov[0] + w0.y * ov[1] + w0.z * ov[2] + w0.w * ov[3]
              + w1.x * ov[4] + w1.y * ov[5] + w1.z * ov[6] + w1.w * ov[7];
      a += __shfl_xor(a, 1, 64);
      a += __shfl_xor(a, 2, 64);
      if ((lane & 3) == 0) zws[n_ln * 264 + Dd] = f2b(a);
    }
  }
}

// ------- k_by: fused b-MFMA -> softmax -> partial-y over 256-s half -------
__global__ __launch_bounds__(512, 4) void k_by(
    const float* __restrict__ x, float* __restrict__ ws)
{
  __shared__ __align__(16) unsigned short zb[16 * 264];  // z bf16, 528 B rows
  __shared__ __align__(16) float ct_all[8 * 256];        // per-wave c-tile [16s][16n]
  __shared__ __align__(16) float ytmp[16 * 260];         // partial y (ds_add target)
  const int tid = threadIdx.x, wave = tid >> 6, lane = tid & 63;
  const int l15 = lane & 15, l4 = lane >> 4;
  const int b = blockIdx.x >> 1, q = blockIdx.x & 1;
  const float* xb = x + (size_t)b * (S_ * D_);
  float* ct = ct_all + wave * 256;

  // load z (8448 B) -> LDS; zero ytmp
  {
    const int4* src = (const int4*)((const unsigned short*)(ws + ZWS_OFF) + (size_t)b * 4224);
    int4* dst = (int4*)zb;
    for (int i = tid; i < 528; i += 512) dst[i] = src[i];
    for (int i = tid; i < 16 * 260; i += 512) ytmp[i] = 0.f;
  }
  __syncthreads();

  float yacc[16][4];
  #pragma unroll
  for (int n = 0; n < 16; ++n) { yacc[n][0]=0.f; yacc[n][1]=0.f; yacc[n][2]=0.f; yacc[n][3]=0.f; }

  for (int t = 0; t < 2; ++t) {
    const int s0 = (q << 8) + ((wave << 1) + t) << 4;  // careful: see fix below
    const int s0f = (q << 8) + (((wave << 1) + t) << 4);
    (void)s0;
    // --- b tile: b[n][s] = sum_D z[n][D] x[s][D] (MFMA 16x16x32 bf16) ---
    floatx4 C = {0.f, 0.f, 0.f, 0.f};
    #pragma unroll
    for (int k = 0; k < 8; ++k) {
      const short8 A = *(const short8*)(zb + l15 * 264 + (k << 5) + (l4 << 3));
      const float* xp = xb + (s0f + l15) * D_ + (k << 5) + (l4 << 3);
      const float4 xv0 = *(const float4*)xp;
      const float4 xv1 = *(const float4*)(xp + 4);
      short8 Bf;
      Bf[0] = (short)f2b(xv0.x); Bf[1] = (short)f2b(xv0.y);
      Bf[2] = (short)f2b(xv0.z); Bf[3] = (short)f2b(xv0.w);
      Bf[4] = (short)f2b(xv1.x); Bf[5] = (short)f2b(xv1.y);
      Bf[6] = (short)f2b(xv1.z); Bf[7] = (short)f2b(xv1.w);
      C = __builtin_amdgcn_mfma_f32_16x16x32_bf16(A, Bf, C, 0, 0, 0);
    }
    // --- softmax over n: C[rg] = b[n=l4*4+rg][s=s0+l15]; reduce regs + xor16/32 ---
    float m = fmaxf(fmaxf(C[0], C[1]), fmaxf(C[2], C[3]));
    m = fmaxf(m, __shfl_xor(m, 16, 64));
    m = fmaxf(m, __shfl_xor(m, 32, 64));
    float e0 = __expf(C[0] - m), e1 = __expf(C[1] - m);
    float e2 = __expf(C[2] - m), e3 = __expf(C[3] - m);
    float sm = e0 + e1 + e2 + e3;
    sm += __shfl_xor(sm, 16, 64);
    sm += __shfl_xor(sm, 32, 64);
    const float inv = 1.f / sm;
    *(float4*)(ct + l15 * 16 + (l4 << 2)) = make_float4(e0*inv, e1*inv, e2*inv, e3*inv);
    __asm__ volatile("s_waitcnt lgkmcnt(0)" ::: "memory");  // wave-local LDS RAW
    // --- y-accum: lane owns D-quad; x re-read is L2-hot ---
    #pragma unroll 4
    for (int s = 0; s < 16; ++s) {
      const float4 xv = *(const float4*)(xb + (s0f + s) * D_ + (lane << 2));
      const float4 c0 = *(const float4*)(ct + s * 16);
      const float4 c1 = *(const float4*)(ct + s * 16 + 4);
      const float4 c2 = *(const float4*)(ct + s * 16 + 8);
      const float4 c3 = *(const float4*)(ct + s * 16 + 12);
      float cf[16];
      cf[0]=c0.x;  cf[1]=c0.y;  cf[2]=c0.z;  cf[3]=c0.w;
      cf[4]=c1.x;  cf[5]=c1.y;  cf[6]=c1.z;  cf[7]=c1.w;
      cf[8]=c2.x;  cf[9]=c2.y;  cf[10]=c2.z; cf[11]=c2.w;
      cf[12]=c3.x; cf[13]=c3.y; cf[14]=c3.z; cf[15]=c3.w;
      #pragma unroll
      for (int n = 0; n < 16; ++n) {
        yacc[n][0] += cf[n] * xv.x; yacc[n][1] += cf[n] * xv.y;
        yacc[n][2] += cf[n] * xv.z; yacc[n][3] += cf[n] * xv.w;
      }
    }
  }
  // cross-wave reduce (compile-time register indices only — r6 spill lesson)
  #pragma unroll
  for (int n = 0; n < 16; ++n) {
    atomicAdd(&ytmp[n * 260 + (lane << 2) + 0], yacc[n][0]);
    atomicAdd(&ytmp[n * 260 + (lane << 2) + 1], yacc[n][1]);
    atomicAdd(&ytmp[n * 260 + (lane << 2) + 2], yacc[n][2]);
    atomicAdd(&ytmp[n * 260 + (lane << 2) + 3], yacc[n][3]);
  }
  __syncthreads();
  // write partial y[b][q][n][D]
  {
    const int n = tid >> 5, d0 = (tid & 31) << 3;
    float* dst = ws + YPART_OFF + ((size_t)(b * 2 + q) * 16 + n) * 256 + d0;
    *(float4*)dst       = *(const float4*)(ytmp + n * 260 + d0);
    *(float4*)(dst + 4) = *(const float4*)(ytmp + n * 260 + d0 + 4);
  }
}

extern "C" void kernel_launch(void* const* d_in, const int* in_sizes, int n_in,
                              void* d_out, int out_size, void* d_ws, size_t ws_size,
                              hipStream_t stream) {
  const float* x = (const float*)d_in[0];   // [256, 512, 256] f32
  const float* W = (const float*)d_in[1];   // [256, 512] f32
  float* out = (float*)d_out;               // [256*512] f32
  float* ws  = (float*)d_ws;                // >= 10.2 MB used
  (void)in_sizes; (void)n_in; (void)out_size; (void)ws_size;

  k_part0<<<512, 512, 0, stream>>>(x, ws);
  k_oz   <<<256, 512, 0, stream>>>(W, ws, out, 0);
  k_by   <<<512, 512, 0, stream>>>(x, ws);
  k_oz   <<<256, 512, 0, stream>>>(W, ws, out, 1);
  k_by   <<<512, 512, 0, stream>>>(x, ws);
  k_oz   <<<256, 512, 0, stream>>>(W, ws, out, 2);
}